// Round 4
// baseline (1094.822 us; speedup 1.0000x reference)
//
#include <hip/hip_runtime.h>
#include <hip/hip_bf16.h>

#define GROUPS 32
#define EPS_GN 1e-5f

// ---------------- f32 tiled GEMM: out[b,o,t] = sum_k W[o,k]*X[b,k,t] + bias[o] ----
#define BM 128
#define BN 128
#define BK 16
#define TM 8
#define TN 8
// 256 threads/block

__device__ __forceinline__ const float* cat_row_ptr(int k, int b,
    const float* r0, const float* r1, const float* r2,
    const float* r3, const float* r4, int n)
{
  // cat = [prop_roi(256), prop_feature(512), fm_short(256), flc(250), conf(250)]
  if (k < 256)  return r0 + ((size_t)b * 256 + k) * n;
  if (k < 768)  return r1 + ((size_t)b * 512 + (k - 256)) * n;
  if (k < 1024) return r2 + ((size_t)b * 256 + (k - 768)) * n;
  if (k < 1274) return r3 + ((size_t)b * 250 + (k - 1024)) * n;
  return r4 + ((size_t)b * 250 + (k - 1274)) * n;
}

template<bool GATHER>
__global__ __launch_bounds__(256)
void gemm_f32(const float* __restrict__ W, const float* __restrict__ X,
              const float* __restrict__ bias, float* __restrict__ out,
              int O, int K, int T,
              const float* r0, const float* r1, const float* r2,
              const float* r3, const float* r4)
{
  __shared__ float As[BK][BM + 4];
  __shared__ float Bs[BK][BN + 4];
  const int b   = blockIdx.z;
  const int om0 = blockIdx.y * BM;
  const int n0  = blockIdx.x * BN;
  const int tid = threadIdx.x;
  const int trow = tid >> 4;       // 0..15
  const int tcol = tid & 15;       // 0..15

  const int a_r = tid >> 1;        // 0..127
  const int a_c = (tid & 1) * 8;   // 0 or 8
  const int b_r = tid >> 4;        // 0..15
  const int b_c = (tid & 15) * 8;  // 0..120

  float acc[TM][TN];
#pragma unroll
  for (int i = 0; i < TM; ++i)
#pragma unroll
    for (int j = 0; j < TN; ++j) acc[i][j] = 0.f;

  const int nK = (K + BK - 1) / BK;
  for (int kt = 0; kt < nK; ++kt) {
    const int k0 = kt * BK;
    // A tile (W), stored transposed As[k][o]
    {
      const float* wp = W + (size_t)(om0 + a_r) * K;
#pragma unroll
      for (int u = 0; u < 8; ++u) {
        const int kk = k0 + a_c + u;
        float v = (kk < K) ? wp[kk] : 0.f;
        As[a_c + u][a_r] = v;
      }
    }
    // B tile (X rows, possibly gathered from 5 sources); dummy row 0 for K-tail
    {
      const int k = k0 + b_r;
      const bool valid = (k < K);
      const int ksafe = valid ? k : 0;
      const float* rp;
      if (GATHER) rp = cat_row_ptr(ksafe, b, r0, r1, r2, r3, r4, T);
      else        rp = X + ((size_t)b * K + ksafe) * T;
#pragma unroll
      for (int u = 0; u < 8; u += 4) {
        float4 v = *(const float4*)(rp + n0 + b_c + u);
        if (!valid) v = make_float4(0.f, 0.f, 0.f, 0.f);
        Bs[b_r][b_c + u + 0] = v.x;
        Bs[b_r][b_c + u + 1] = v.y;
        Bs[b_r][b_c + u + 2] = v.z;
        Bs[b_r][b_c + u + 3] = v.w;
      }
    }
    __syncthreads();
#pragma unroll
    for (int kk = 0; kk < BK; ++kk) {
      float a[TM], bb[TN];
#pragma unroll
      for (int i = 0; i < TM; ++i) a[i] = As[kk][trow * TM + i];
#pragma unroll
      for (int j = 0; j < TN; ++j) bb[j] = Bs[kk][tcol * TN + j];
#pragma unroll
      for (int i = 0; i < TM; ++i)
#pragma unroll
        for (int j = 0; j < TN; ++j) acc[i][j] = fmaf(a[i], bb[j], acc[i][j]);
    }
    __syncthreads();
  }
#pragma unroll
  for (int i = 0; i < TM; ++i) {
    const int o = om0 + trow * TM + i;
    const float bs = bias[o];
    float* op = out + ((size_t)b * O + o) * T + n0 + tcol * TN;
#pragma unroll
    for (int j = 0; j < TN; ++j) op[j] = acc[i][j] + bs;
  }
}

// ---------------- GroupNorm(+ReLU) in-place over [B,C,Tn], one block per (b,group) --
__global__ __launch_bounds__(256)
void gn_relu_inplace(float* __restrict__ x, const float* __restrict__ gamma,
                     const float* __restrict__ beta, int C, int Tn, int tshift)
{
  const int b = blockIdx.x / GROUPS;
  const int g = blockIdx.x % GROUPS;
  const int Cg = C / GROUPS;
  const size_t base = ((size_t)b * C + (size_t)g * Cg) * Tn;
  const int M = Cg * Tn;
  const int tid = threadIdx.x;

  float sum = 0.f, ss = 0.f;
  for (int i = tid * 4; i < M; i += 256 * 4) {
    float4 v = *(const float4*)(x + base + i);
    sum += v.x + v.y + v.z + v.w;
    ss  += v.x * v.x + v.y * v.y + v.z * v.z + v.w * v.w;
  }
#pragma unroll
  for (int off = 32; off > 0; off >>= 1) {
    sum += __shfl_down(sum, off);
    ss  += __shfl_down(ss, off);
  }
  __shared__ float s1[4], s2[4];
  __shared__ float smean, sinv;
  const int wid = tid >> 6, lane = tid & 63;
  if (lane == 0) { s1[wid] = sum; s2[wid] = ss; }
  __syncthreads();
  if (tid == 0) {
    float t1 = s1[0] + s1[1] + s1[2] + s1[3];
    float t2 = s2[0] + s2[1] + s2[2] + s2[3];
    float mean = t1 / (float)M;
    float var  = t2 / (float)M - mean * mean;
    smean = mean;
    sinv  = rsqrtf(var + EPS_GN);
  }
  __syncthreads();
  const float mean = smean, inv = sinv;
  for (int i = tid * 4; i < M; i += 256 * 4) {
    float4 v = *(const float4*)(x + base + i);
    const int ch = g * Cg + (i >> tshift);
    const float sc = gamma[ch] * inv;
    const float sh = beta[ch] - mean * sc;
    v.x = fmaxf(v.x * sc + sh, 0.f);
    v.y = fmaxf(v.y * sc + sh, 0.f);
    v.z = fmaxf(v.z * sc + sh, 0.f);
    v.w = fmaxf(v.w * sc + sh, 0.f);
    *(float4*)(x + base + i) = v;
  }
}

// ---------------- block maxima (granularity 32) ----------------
__global__ __launch_bounds__(256)
void blockmax_kernel(const float* __restrict__ x, float* __restrict__ mx,
                     int T, int TB, int total)
{
  int idx = blockIdx.x * 256 + threadIdx.x;
  if (idx >= total) return;
  int row = idx / TB;
  int tb  = idx - row * TB;
  const float* p = x + (size_t)row * T + (size_t)tb * 32;
  float m = p[0];
#pragma unroll
  for (int j = 1; j < 32; ++j) m = fmaxf(m, p[j]);
  mx[idx] = m;
}

// ---------------- boundary max pooling: out[b,c,n] = max x[b,c, s..e] -------------
__global__ __launch_bounds__(256)
void pool_kernel(const float* __restrict__ x, const float* __restrict__ mx,
                 const float* __restrict__ segs, float* __restrict__ out,
                 int C, int T, int TB, int half, int N)
{
  const int n = blockIdx.x * 256 + threadIdx.x;
  const int c = blockIdx.y;
  const int b = blockIdx.z;
  const float4 sg = *(const float4*)(segs + ((size_t)b * N + n) * 4);
  float f0, f1;
  if (c < half) { f0 = sg.x; f1 = sg.y; }
  else          { f0 = sg.z; f1 = sg.w; }
  int s = (int)floorf(f0);
  s = min(max(s, 0), T - 1);
  int e = (int)ceilf(f1);
  e = min(max(e, 0), T - 1);
  e = max(e, s);
  const float* row  = x  + ((size_t)b * C + c) * T;
  const float* mrow = mx + ((size_t)b * C + c) * TB;
  float m = -3.402823466e38f;
  const int b0 = s >> 5, b1 = e >> 5;
  if (b0 == b1) {
    for (int t = s; t <= e; ++t) m = fmaxf(m, row[t]);
  } else {
    const int t0e = (b0 + 1) << 5;
    for (int t = s; t < t0e; ++t) m = fmaxf(m, row[t]);
    for (int bb = b0 + 1; bb < b1; ++bb) m = fmaxf(m, mrow[bb]);
    for (int t = b1 << 5; t <= e; ++t) m = fmaxf(m, row[t]);
  }
  out[((size_t)b * C + c) * N + n] = m;
}

extern "C" void kernel_launch(void* const* d_in, const int* in_sizes, int n_in,
                              void* d_out, int out_size, void* d_ws, size_t ws_size,
                              hipStream_t stream)
{
  (void)in_sizes; (void)n_in; (void)out_size; (void)ws_size;

  const float* feature  = (const float*)d_in[0];   // [4,512,2048]
  const float* frame    = (const float*)d_in[1];   // [4,256,4096]
  const float* segments = (const float*)d_in[2];   // [4,2048,4]
  const float* fsegs    = (const float*)d_in[3];   // [4,2048,4]
  const float* flc      = (const float*)d_in[4];   // [4,250,2048]
  const float* conf     = (const float*)d_in[5];   // [4,250,2048]
  const float* w_cur  = (const float*)d_in[6];
  const float* b_cur  = (const float*)d_in[7];
  const float* g_cur  = (const float*)d_in[8];
  const float* be_cur = (const float*)d_in[9];
  const float* w_lr   = (const float*)d_in[10];
  const float* b_lr   = (const float*)d_in[11];
  const float* g_lr   = (const float*)d_in[12];
  const float* be_lr  = (const float*)d_in[13];
  const float* w_roi  = (const float*)d_in[14];
  const float* b_roi  = (const float*)d_in[15];
  const float* g_roi  = (const float*)d_in[16];
  const float* be_roi = (const float*)d_in[17];
  const float* w_prop = (const float*)d_in[18];
  const float* b_prop = (const float*)d_in[19];
  const float* g_prop = (const float*)d_in[20];
  const float* be_prop= (const float*)d_in[21];

  // Outputs are FLOAT32 (verified round 3): [out0 | feat], 4*512*2048 each.
  float* OUT0 = (float*)d_out;             // final block output
  float* FOUT = (float*)d_out + 4194304;   // feat

  // workspace layout (floats)
  float* ws  = (float*)d_ws;
  float* Y1  = ws;                 // fm_short            2097152
  float* PF  = Y1 + 2097152;       // prop_feature        4194304
  float* RP  = PF + 4194304;       // roi pooled          2097152
  float* RF  = RP + 2097152;       // roi block out       2097152
  float* MXF = RF + 2097152;       // blockmax(feat)      131072
  float* MXR = MXF + 131072;       // blockmax(frame)     131072
  // total ~43 MB

  const float* nul = nullptr;

  // 1) fm_short = relu(GN(conv(feature, w_cur)))
  gemm_f32<false><<<dim3(16, 2, 4), 256, 0, stream>>>(
      w_cur, feature, b_cur, Y1, 256, 512, 2048, nul, nul, nul, nul, nul);
  gn_relu_inplace<<<dim3(128), 256, 0, stream>>>(Y1, g_cur, be_cur, 256, 2048, 11);

  // 2) feat = relu(GN(conv(feature, w_lr)))  -> output 1 (f32, direct)
  gemm_f32<false><<<dim3(16, 4, 4), 256, 0, stream>>>(
      w_lr, feature, b_lr, FOUT, 512, 512, 2048, nul, nul, nul, nul, nul);
  gn_relu_inplace<<<dim3(128), 256, 0, stream>>>(FOUT, g_lr, be_lr, 512, 2048, 11);

  // 3) prop_feature = boundary_max_pooling(feat, segments)
  blockmax_kernel<<<dim3(512), 256, 0, stream>>>(FOUT, MXF, 2048, 64, 131072);
  pool_kernel<<<dim3(8, 512, 4), 256, 0, stream>>>(
      FOUT, MXF, segments, PF, 512, 2048, 64, 256, 2048);

  // 4) prop_roi = boundary_max_pooling(frame_level_feature, frame_segments)
  blockmax_kernel<<<dim3(512), 256, 0, stream>>>(frame, MXR, 4096, 128, 131072);
  pool_kernel<<<dim3(8, 256, 4), 256, 0, stream>>>(
      frame, MXR, fsegs, RP, 256, 4096, 128, 128, 2048);

  // 5) prop_roi = relu(GN(conv(prop_roi, w_roi)))
  gemm_f32<false><<<dim3(16, 2, 4), 256, 0, stream>>>(
      w_roi, RP, b_roi, RF, 256, 256, 2048, nul, nul, nul, nul, nul);
  gn_relu_inplace<<<dim3(128), 256, 0, stream>>>(RF, g_roi, be_roi, 256, 2048, 11);

  // 6) out0 = relu(GN(conv(cat, w_prop)))  (gathered K=1524, direct to d_out)
  gemm_f32<true><<<dim3(16, 4, 4), 256, 0, stream>>>(
      w_prop, nul, b_prop, OUT0, 512, 1524, 2048, RF, PF, Y1, flc, conf);
  gn_relu_inplace<<<dim3(128), 256, 0, stream>>>(OUT0, g_prop, be_prop, 512, 2048, 11);
}

// Round 6
// 672.340 us; speedup vs baseline: 1.6284x; 1.6284x over previous
//
#include <hip/hip_runtime.h>
#include <hip/hip_bf16.h>

#define GROUPS 32
#define EPS_GN 1e-5f

typedef short bf16x8 __attribute__((ext_vector_type(8)));
typedef float f32x4 __attribute__((ext_vector_type(4)));

__device__ __forceinline__ ushort to_bf16_bits(float v) {
  __hip_bfloat16 h = __float2bfloat16(v);
  return *(ushort*)&h;
}

__device__ __forceinline__ const float* cat_row_ptr(int k, int b,
    const float* r0, const float* r1, const float* r2,
    const float* r3, const float* r4, int n)
{
  // cat = [prop_roi(256)=RF, prop_feature(512)=PF, fm_short(256)=Y1, flc(250), conf(250)]
  if (k < 256)  return r0 + ((size_t)b * 256 + k) * n;
  if (k < 768)  return r1 + ((size_t)b * 512 + (k - 256)) * n;
  if (k < 1024) return r2 + ((size_t)b * 256 + (k - 768)) * n;
  if (k < 1274) return r3 + ((size_t)b * 250 + (k - 1024)) * n;
  return r4 + ((size_t)b * 250 + (k - 1274)) * n;
}

// ---------------- weight cast f32 [O][K] -> bf16 [O][Kp] (zero pad K..Kp) --------
__global__ __launch_bounds__(256)
void cast_w_kernel(const float* __restrict__ w, ushort* __restrict__ wb,
                   int K, int Kp, int total)
{
  int idx = blockIdx.x * 256 + threadIdx.x;
  if (idx >= total) return;
  int o = idx / Kp, k = idx - o * Kp;
  float v = (k < K) ? w[(size_t)o * K + k] : 0.f;
  wb[idx] = to_bf16_bits(v);
}

// ---------------- transpose+cast: f32 [B][C][T] -> bf16 [B][T][C] ----------------
__global__ __launch_bounds__(256)
void transpose_cast_kernel(const float* __restrict__ src, ushort* __restrict__ dst,
                           int C, int T)
{
  __shared__ float tile[32][33];
  const int b = blockIdx.z;
  const int c0 = blockIdx.y * 32, t0 = blockIdx.x * 32;
  const int tx = threadIdx.x & 31, ty = threadIdx.x >> 5;   // 32 x 8
#pragma unroll
  for (int i = 0; i < 4; ++i)
    tile[ty + 8 * i][tx] = src[((size_t)b * C + c0 + ty + 8 * i) * T + t0 + tx];
  __syncthreads();
#pragma unroll
  for (int i = 0; i < 4; ++i)
    dst[((size_t)b * T + t0 + ty + 8 * i) * C + c0 + tx] =
        to_bf16_bits(tile[tx][ty + 8 * i]);
}

// ---------------- gathered transpose+cast into cat_t [B][T][1536] ----------------
__global__ __launch_bounds__(256)
void transpose_cat_kernel(const float* __restrict__ r0, const float* __restrict__ r1,
                          const float* __restrict__ r2, const float* __restrict__ r3,
                          const float* __restrict__ r4, ushort* __restrict__ dst, int T)
{
  __shared__ float tile[32][33];
  const int b = blockIdx.z;
  const int k0 = blockIdx.y * 32, t0 = blockIdx.x * 32;
  const int tx = threadIdx.x & 31, ty = threadIdx.x >> 5;
#pragma unroll
  for (int i = 0; i < 4; ++i) {
    const int k = k0 + ty + 8 * i;
    float v = 0.f;
    if (k < 1524) {
      const float* rp = cat_row_ptr(k, b, r0, r1, r2, r3, r4, T);
      v = rp[t0 + tx];
    }
    tile[ty + 8 * i][tx] = v;
  }
  __syncthreads();
#pragma unroll
  for (int i = 0; i < 4; ++i)
    dst[((size_t)b * T + t0 + ty + 8 * i) * 1536 + k0 + tx] =
        to_bf16_bits(tile[tx][ty + 8 * i]);
}

// ---------------- bf16 MFMA GEMM: out[b,o,t] = sum_k W[o,k]*Xt[b,t,k] + bias[o] --
// block 256 thr = 4 waves (2x2), block tile 128x128, wave tile 64x64.
// A-frag (W): lane l -> row o=(l&15), k=(l>>4)*8..+8 contiguous.
// B-frag (Xt): lane l -> col t=(l&15), k contiguous.
// C/D: col(t)=lane&15, row(o)=(lane>>4)*4+reg  [verified m89].
__global__ __launch_bounds__(256)
void mfma_gemm(const ushort* __restrict__ Wb, const ushort* __restrict__ Xt,
               const float* __restrict__ bias, float* __restrict__ out,
               int O, int K, int T)
{
  const int b  = blockIdx.z;
  const int o0 = blockIdx.y * 128;
  const int t0 = blockIdx.x * 128;
  const int lane = threadIdx.x & 63;
  const int wid  = threadIdx.x >> 6;
  const int wm = wid >> 1, wn = wid & 1;
  const int lr = lane & 15;
  const int lq = lane >> 4;

  const ushort* wp = Wb + (size_t)(o0 + wm * 64 + lr) * K + lq * 8;
  const ushort* xp = Xt + ((size_t)b * T + t0 + wn * 64 + lr) * K + lq * 8;

  f32x4 acc[4][4];
#pragma unroll
  for (int i = 0; i < 4; ++i)
#pragma unroll
    for (int j = 0; j < 4; ++j) acc[i][j] = (f32x4){0.f, 0.f, 0.f, 0.f};

  for (int k0 = 0; k0 < K; k0 += 32) {
    bf16x8 a[4], bt[4];
#pragma unroll
    for (int i = 0; i < 4; ++i)
      a[i] = *(const bf16x8*)(wp + (size_t)i * 16 * K + k0);
#pragma unroll
    for (int j = 0; j < 4; ++j)
      bt[j] = *(const bf16x8*)(xp + (size_t)j * 16 * K + k0);
#pragma unroll
    for (int i = 0; i < 4; ++i)
#pragma unroll
      for (int j = 0; j < 4; ++j)
        acc[i][j] = __builtin_amdgcn_mfma_f32_16x16x32_bf16(a[i], bt[j], acc[i][j], 0, 0, 0);
  }

#pragma unroll
  for (int i = 0; i < 4; ++i) {
#pragma unroll
    for (int r = 0; r < 4; ++r) {
      const int o = o0 + wm * 64 + i * 16 + lq * 4 + r;
      const float bs = bias[o];
      float* op = out + ((size_t)b * O + o) * T + t0 + wn * 64 + lr;
#pragma unroll
      for (int j = 0; j < 4; ++j) op[j * 16] = acc[i][j][r] + bs;
    }
  }
}

// ---------------- GroupNorm(+ReLU) in-place over [B,C,Tn] ------------------------
__global__ __launch_bounds__(256)
void gn_relu_inplace(float* __restrict__ x, const float* __restrict__ gamma,
                     const float* __restrict__ beta, int C, int Tn, int tshift)
{
  const int b = blockIdx.x / GROUPS;
  const int g = blockIdx.x % GROUPS;
  const int Cg = C / GROUPS;
  const size_t base = ((size_t)b * C + (size_t)g * Cg) * Tn;
  const int M = Cg * Tn;
  const int tid = threadIdx.x;

  float sum = 0.f, ss = 0.f;
  for (int i = tid * 4; i < M; i += 256 * 4) {
    float4 v = *(const float4*)(x + base + i);
    sum += v.x + v.y + v.z + v.w;
    ss  += v.x * v.x + v.y * v.y + v.z * v.z + v.w * v.w;
  }
#pragma unroll
  for (int off = 32; off > 0; off >>= 1) {
    sum += __shfl_down(sum, off);
    ss  += __shfl_down(ss, off);
  }
  __shared__ float s1[4], s2[4];
  __shared__ float smean, sinv;
  const int wid = tid >> 6, lane = tid & 63;
  if (lane == 0) { s1[wid] = sum; s2[wid] = ss; }
  __syncthreads();
  if (tid == 0) {
    float t1 = s1[0] + s1[1] + s1[2] + s1[3];
    float t2 = s2[0] + s2[1] + s2[2] + s2[3];
    float mean = t1 / (float)M;
    float var  = t2 / (float)M - mean * mean;
    smean = mean;
    sinv  = rsqrtf(var + EPS_GN);
  }
  __syncthreads();
  const float mean = smean, inv = sinv;
  for (int i = tid * 4; i < M; i += 256 * 4) {
    float4 v = *(const float4*)(x + base + i);
    const int ch = g * Cg + (i >> tshift);
    const float sc = gamma[ch] * inv;
    const float sh = beta[ch] - mean * sc;
    v.x = fmaxf(v.x * sc + sh, 0.f);
    v.y = fmaxf(v.y * sc + sh, 0.f);
    v.z = fmaxf(v.z * sc + sh, 0.f);
    v.w = fmaxf(v.w * sc + sh, 0.f);
    *(float4*)(x + base + i) = v;
  }
}

// ---------------- block maxima (granularity 32) ----------------
__global__ __launch_bounds__(256)
void blockmax_kernel(const float* __restrict__ x, float* __restrict__ mx,
                     int T, int TB, int total)
{
  int idx = blockIdx.x * 256 + threadIdx.x;
  if (idx >= total) return;
  int row = idx / TB;
  int tb  = idx - row * TB;
  const float* p = x + (size_t)row * T + (size_t)tb * 32;
  float m = p[0];
#pragma unroll
  for (int j = 1; j < 32; ++j) m = fmaxf(m, p[j]);
  mx[idx] = m;
}

// ---------------- boundary max pooling: out[b,c,n] = max x[b,c, s..e] ------------
__global__ __launch_bounds__(256)
void pool_kernel(const float* __restrict__ x, const float* __restrict__ mx,
                 const float* __restrict__ segs, float* __restrict__ out,
                 int C, int T, int TB, int half, int N)
{
  const int n = blockIdx.x * 256 + threadIdx.x;
  const int c = blockIdx.y;
  const int b = blockIdx.z;
  const float4 sg = *(const float4*)(segs + ((size_t)b * N + n) * 4);
  float f0, f1;
  if (c < half) { f0 = sg.x; f1 = sg.y; }
  else          { f0 = sg.z; f1 = sg.w; }
  int s = (int)floorf(f0);
  s = min(max(s, 0), T - 1);
  int e = (int)ceilf(f1);
  e = min(max(e, 0), T - 1);
  e = max(e, s);
  const float* row  = x  + ((size_t)b * C + c) * T;
  const float* mrow = mx + ((size_t)b * C + c) * TB;
  float m = -3.402823466e38f;
  const int b0 = s >> 5, b1 = e >> 5;
  if (b0 == b1) {
    for (int t = s; t <= e; ++t) m = fmaxf(m, row[t]);
  } else {
    const int t0e = (b0 + 1) << 5;
    for (int t = s; t < t0e; ++t) m = fmaxf(m, row[t]);
    for (int bb = b0 + 1; bb < b1; ++bb) m = fmaxf(m, mrow[bb]);
    for (int t = b1 << 5; t <= e; ++t) m = fmaxf(m, row[t]);
  }
  out[((size_t)b * C + c) * N + n] = m;
}

extern "C" void kernel_launch(void* const* d_in, const int* in_sizes, int n_in,
                              void* d_out, int out_size, void* d_ws, size_t ws_size,
                              hipStream_t stream)
{
  (void)in_sizes; (void)n_in; (void)out_size; (void)ws_size;

  const float* feature  = (const float*)d_in[0];   // [4,512,2048]
  const float* frame    = (const float*)d_in[1];   // [4,256,4096]
  const float* segments = (const float*)d_in[2];   // [4,2048,4]
  const float* fsegs    = (const float*)d_in[3];   // [4,2048,4]
  const float* flc      = (const float*)d_in[4];   // [4,250,2048]
  const float* conf     = (const float*)d_in[5];   // [4,250,2048]
  const float* w_cur  = (const float*)d_in[6];
  const float* b_cur  = (const float*)d_in[7];
  const float* g_cur  = (const float*)d_in[8];
  const float* be_cur = (const float*)d_in[9];
  const float* w_lr   = (const float*)d_in[10];
  const float* b_lr   = (const float*)d_in[11];
  const float* g_lr   = (const float*)d_in[12];
  const float* be_lr  = (const float*)d_in[13];
  const float* w_roi  = (const float*)d_in[14];
  const float* b_roi  = (const float*)d_in[15];
  const float* g_roi  = (const float*)d_in[16];
  const float* be_roi = (const float*)d_in[17];
  const float* w_prop = (const float*)d_in[18];
  const float* b_prop = (const float*)d_in[19];
  const float* g_prop = (const float*)d_in[20];
  const float* be_prop= (const float*)d_in[21];

  // Outputs are FLOAT32: [out0 | feat], 4*512*2048 each.
  float* OUT0 = (float*)d_out;
  float* FOUT = (float*)d_out + 4194304;

  // ---- workspace layout ----
  float* ws  = (float*)d_ws;
  float* Y1  = ws;                 // fm_short   4*256*2048
  float* PF  = Y1 + 2097152;       // prop_feature 4*512*2048
  float* RP  = PF + 4194304;       // roi pooled 4*256*2048
  float* RF  = RP + 2097152;       // roi block  4*256*2048
  float* MXF = RF + 2097152;       // blockmax(feat)  131072
  float* MXR = MXF + 131072;       // blockmax(frame) 131072
  ushort* FT   = (ushort*)(MXR + 131072);    // feature_t [4][2048][512]
  ushort* RPT  = FT + 4194304;               // RP_t      [4][2048][256]
  ushort* CATT = RPT + 2097152;              // cat_t     [4][2048][1536]
  ushort* WCB  = CATT + 12582912;            // w_cur bf16 [256][512]
  ushort* WLB  = WCB + 131072;               // w_lr  bf16 [512][512]
  ushort* WRB  = WLB + 262144;               // w_roi bf16 [256][256]
  ushort* WPB  = WRB + 65536;                // w_prop bf16 [512][1536] padded
  // total ~83 MB

  // ---- weight casts (independent of activations) ----
  cast_w_kernel<<<dim3(512),  256, 0, stream>>>(w_cur,  WCB, 512, 512, 131072);
  cast_w_kernel<<<dim3(1024), 256, 0, stream>>>(w_lr,   WLB, 512, 512, 262144);
  cast_w_kernel<<<dim3(256),  256, 0, stream>>>(w_roi,  WRB, 256, 256, 65536);
  cast_w_kernel<<<dim3(3072), 256, 0, stream>>>(w_prop, WPB, 1524, 1536, 786432);

  // ---- feature -> feature_t ----
  transpose_cast_kernel<<<dim3(64, 16, 4), 256, 0, stream>>>(feature, FT, 512, 2048);

  // 1) fm_short = relu(GN(conv(feature, w_cur)))
  mfma_gemm<<<dim3(16, 2, 4), 256, 0, stream>>>(WCB, FT, b_cur, Y1, 256, 512, 2048);
  gn_relu_inplace<<<dim3(128), 256, 0, stream>>>(Y1, g_cur, be_cur, 256, 2048, 11);

  // 2) feat = relu(GN(conv(feature, w_lr)))  -> output 1
  mfma_gemm<<<dim3(16, 4, 4), 256, 0, stream>>>(WLB, FT, b_lr, FOUT, 512, 512, 2048);
  gn_relu_inplace<<<dim3(128), 256, 0, stream>>>(FOUT, g_lr, be_lr, 512, 2048, 11);

  // 3) prop_feature = boundary_max_pooling(feat, segments)
  blockmax_kernel<<<dim3(512), 256, 0, stream>>>(FOUT, MXF, 2048, 64, 131072);
  pool_kernel<<<dim3(8, 512, 4), 256, 0, stream>>>(
      FOUT, MXF, segments, PF, 512, 2048, 64, 256, 2048);

  // 4) prop_roi = boundary_max_pooling(frame_level_feature, frame_segments)
  blockmax_kernel<<<dim3(512), 256, 0, stream>>>(frame, MXR, 4096, 128, 131072);
  pool_kernel<<<dim3(8, 256, 4), 256, 0, stream>>>(
      frame, MXR, fsegs, RP, 256, 4096, 128, 128, 2048);

  // 5) prop_roi = relu(GN(conv(prop_roi, w_roi)))
  transpose_cast_kernel<<<dim3(64, 8, 4), 256, 0, stream>>>(RP, RPT, 256, 2048);
  mfma_gemm<<<dim3(16, 2, 4), 256, 0, stream>>>(WRB, RPT, b_roi, RF, 256, 256, 2048);
  gn_relu_inplace<<<dim3(128), 256, 0, stream>>>(RF, g_roi, be_roi, 256, 2048, 11);

  // 6) out0 = relu(GN(conv(cat, w_prop)))
  transpose_cat_kernel<<<dim3(64, 48, 4), 256, 0, stream>>>(RF, PF, Y1, flc, conf,
                                                            CATT, 2048);
  mfma_gemm<<<dim3(16, 4, 4), 256, 0, stream>>>(WPB, CATT, b_prop, OUT0, 512, 1536, 2048);
  gn_relu_inplace<<<dim3(128), 256, 0, stream>>>(OUT0, g_prop, be_prop, 512, 2048, 11);
}

// Round 9
// 482.775 us; speedup vs baseline: 2.2678x; 1.3927x over previous
//
#include <hip/hip_runtime.h>
#include <hip/hip_bf16.h>

#define GROUPS 32
#define EPS_GN 1e-5f

typedef short bf16x8 __attribute__((ext_vector_type(8)));
typedef float f32x4 __attribute__((ext_vector_type(4)));

__device__ __forceinline__ ushort to_bf16_bits(float v) {
  __hip_bfloat16 h = __float2bfloat16(v);
  return *(ushort*)&h;
}
__device__ __forceinline__ float bflo(unsigned u) { return __uint_as_float(u << 16); }
__device__ __forceinline__ float bfhi(unsigned u) { return __uint_as_float(u & 0xffff0000u); }
__device__ __forceinline__ ushort bfpack(float f) {
  return (ushort)(__float_as_uint(f) >> 16);   // exact: values originate from bf16
}

// ---------------- weight cast f32 [O][K] -> bf16 [O][Kp] (zero pad K..Kp) --------
__global__ __launch_bounds__(256)
void cast_w_kernel(const float* __restrict__ w, ushort* __restrict__ wb,
                   int K, int Kp, int total)
{
  int idx = blockIdx.x * 256 + threadIdx.x;
  if (idx >= total) return;
  int o = idx / Kp, k = idx - o * Kp;
  float v = (k < K) ? w[(size_t)o * K + k] : 0.f;
  wb[idx] = to_bf16_bits(v);
}

// ------- transpose+cast with offset: f32 [B][C][T] -> bf16 dst[b][t][coff+c] -----
__global__ __launch_bounds__(256)
void transpose_cast_off(const float* __restrict__ src, ushort* __restrict__ dst,
                        int C, int T, int dstride, int coff, int Cpad)
{
  __shared__ float tile[32][33];
  const int b = blockIdx.z;
  const int c0 = blockIdx.y * 32, t0 = blockIdx.x * 32;
  const int tx = threadIdx.x & 31, ty = threadIdx.x >> 5;   // 32 x 8
#pragma unroll
  for (int i = 0; i < 4; ++i) {
    const int c = c0 + ty + 8 * i;
    tile[ty + 8 * i][tx] = (c < C) ? src[((size_t)b * C + c) * T + t0 + tx] : 0.f;
  }
  __syncthreads();
  const int cw = c0 + tx;
  if (cw >= Cpad) return;
#pragma unroll
  for (int i = 0; i < 4; ++i)
    dst[((size_t)b * T + t0 + ty + 8 * i) * dstride + coff + cw] =
        to_bf16_bits(tile[tx][ty + 8 * i]);
}

// ---------------- block maxima over t (granularity 32), transposed bf16 ----------
// xt [B][T][C] -> bx [B][TB][C];  8 channels per thread
__global__ __launch_bounds__(256)
void bmxt_kernel(const ushort* __restrict__ xt, ushort* __restrict__ bx,
                 int C, int T, int TB, int total8)
{
  int idx = blockIdx.x * 256 + threadIdx.x;
  if (idx >= total8) return;
  const int nc8 = C >> 3;
  const int ci = idx % nc8;
  const int rt = idx / nc8;            // b*TB + tb
  const int tb = rt % TB, b = rt / TB;
  const ushort* p = xt + ((size_t)b * T + (size_t)tb * 32) * C + ci * 8;
  float m[8];
#pragma unroll
  for (int i = 0; i < 8; ++i) m[i] = -3.402823466e38f;
  for (int j = 0; j < 32; ++j) {
    const uint4 v = *(const uint4*)(p + (size_t)j * C);
    m[0] = fmaxf(m[0], bflo(v.x)); m[1] = fmaxf(m[1], bfhi(v.x));
    m[2] = fmaxf(m[2], bflo(v.y)); m[3] = fmaxf(m[3], bfhi(v.y));
    m[4] = fmaxf(m[4], bflo(v.z)); m[5] = fmaxf(m[5], bfhi(v.z));
    m[6] = fmaxf(m[6], bflo(v.w)); m[7] = fmaxf(m[7], bfhi(v.w));
  }
  uint4 o;
  o.x = (unsigned)bfpack(m[0]) | ((unsigned)bfpack(m[1]) << 16);
  o.y = (unsigned)bfpack(m[2]) | ((unsigned)bfpack(m[3]) << 16);
  o.z = (unsigned)bfpack(m[4]) | ((unsigned)bfpack(m[5]) << 16);
  o.w = (unsigned)bfpack(m[6]) | ((unsigned)bfpack(m[7]) << 16);
  *(uint4*)(bx + (size_t)rt * C + ci * 8) = o;
}

// ------- transposed boundary max pool: one WAVE per (n, half) — uniform (s,e) -----
// xt [B][T][C], bx [B][TB][C]; out dst[(b*N+n)*dstride + coff + c], bf16
// CHL channels per lane; INVARIANT: 64*CHL == C/2.  CHL=4 (uint2) or CHL=2 (uint).
template<int CHL>
__global__ __launch_bounds__(256)
void pool_t_kernel(const ushort* __restrict__ xt, const ushort* __restrict__ bx,
                   const float* __restrict__ segs, ushort* __restrict__ dst,
                   int C, int T, int TB, int N, int dstride, int coff)
{
  const int b    = blockIdx.z;
  const int half = blockIdx.y;
  const int n    = blockIdx.x * 4 + (threadIdx.x >> 6);
  const int lane = threadIdx.x & 63;
  const int c    = half * (C >> 1) + lane * CHL;

  const float4 sg = *(const float4*)(segs + ((size_t)b * N + n) * 4);
  const float f0 = half ? sg.z : sg.x;
  const float f1 = half ? sg.w : sg.y;
  int s = min(max((int)floorf(f0), 0), T - 1);
  int e = min(max((int)ceilf(f1), 0), T - 1);
  e = max(e, s);

  const ushort* xp = xt + (size_t)b * T * C + c;
  const ushort* bp = bx + (size_t)b * TB * C + c;
  float m[CHL];
#pragma unroll
  for (int i = 0; i < CHL; ++i) m[i] = -3.402823466e38f;

  auto acc = [&](const ushort* p) {
    if constexpr (CHL == 4) {
      const uint2 v = *(const uint2*)p;
      m[0] = fmaxf(m[0], bflo(v.x)); m[1] = fmaxf(m[1], bfhi(v.x));
      m[2] = fmaxf(m[2], bflo(v.y)); m[3] = fmaxf(m[3], bfhi(v.y));
    } else {
      const unsigned v = *(const unsigned*)p;
      m[0] = fmaxf(m[0], bflo(v)); m[1] = fmaxf(m[1], bfhi(v));
    }
  };

  const int b0 = s >> 5, b1 = e >> 5;
  if (b0 == b1) {
    for (int t = s; t <= e; ++t) acc(xp + (size_t)t * C);
  } else {
    const int t0e = (b0 + 1) << 5;
    for (int t = s; t < t0e; ++t) acc(xp + (size_t)t * C);
    for (int bb = b0 + 1; bb < b1; ++bb) acc(bp + (size_t)bb * C);
    for (int t = (b1 << 5); t <= e; ++t) acc(xp + (size_t)t * C);
  }

  ushort* op = dst + ((size_t)b * N + n) * dstride + coff + c;
  if constexpr (CHL == 4) {
    uint2 o;
    o.x = (unsigned)bfpack(m[0]) | ((unsigned)bfpack(m[1]) << 16);
    o.y = (unsigned)bfpack(m[2]) | ((unsigned)bfpack(m[3]) << 16);
    *(uint2*)op = o;
  } else {
    *(unsigned*)op = (unsigned)bfpack(m[0]) | ((unsigned)bfpack(m[1]) << 16);
  }
}

// ---------------- bf16 MFMA GEMM: out[b,o,t] = sum_k W[o,k]*Xt[b,t,k] + bias[o] --
__global__ __launch_bounds__(256)
void mfma_gemm(const ushort* __restrict__ Wb, const ushort* __restrict__ Xt,
               const float* __restrict__ bias, float* __restrict__ out,
               int O, int K, int T)
{
  const int b  = blockIdx.z;
  const int o0 = blockIdx.y * 128;
  const int t0 = blockIdx.x * 128;
  const int lane = threadIdx.x & 63;
  const int wid  = threadIdx.x >> 6;
  const int wm = wid >> 1, wn = wid & 1;
  const int lr = lane & 15;
  const int lq = lane >> 4;

  const ushort* wp = Wb + (size_t)(o0 + wm * 64 + lr) * K + lq * 8;
  const ushort* xp = Xt + ((size_t)b * T + t0 + wn * 64 + lr) * K + lq * 8;

  f32x4 acc[4][4];
#pragma unroll
  for (int i = 0; i < 4; ++i)
#pragma unroll
    for (int j = 0; j < 4; ++j) acc[i][j] = (f32x4){0.f, 0.f, 0.f, 0.f};

  for (int k0 = 0; k0 < K; k0 += 32) {
    bf16x8 a[4], bt[4];
#pragma unroll
    for (int i = 0; i < 4; ++i)
      a[i] = *(const bf16x8*)(wp + (size_t)i * 16 * K + k0);
#pragma unroll
    for (int j = 0; j < 4; ++j)
      bt[j] = *(const bf16x8*)(xp + (size_t)j * 16 * K + k0);
#pragma unroll
    for (int i = 0; i < 4; ++i)
#pragma unroll
      for (int j = 0; j < 4; ++j)
        acc[i][j] = __builtin_amdgcn_mfma_f32_16x16x32_bf16(a[i], bt[j], acc[i][j], 0, 0, 0);
  }

#pragma unroll
  for (int i = 0; i < 4; ++i) {
#pragma unroll
    for (int r = 0; r < 4; ++r) {
      const int o = o0 + wm * 64 + i * 16 + lq * 4 + r;
      const float bs = bias[o];
      float* op = out + ((size_t)b * O + o) * T + t0 + wn * 64 + lr;
#pragma unroll
      for (int j = 0; j < 4; ++j) op[j * 16] = acc[i][j][r] + bs;
    }
  }
}

// ---------------- GroupNorm(+ReLU) in-place over [B,C,Tn] ------------------------
__global__ __launch_bounds__(256)
void gn_relu_inplace(float* __restrict__ x, const float* __restrict__ gamma,
                     const float* __restrict__ beta, int C, int Tn, int tshift)
{
  const int b = blockIdx.x / GROUPS;
  const int g = blockIdx.x % GROUPS;
  const int Cg = C / GROUPS;
  const size_t base = ((size_t)b * C + (size_t)g * Cg) * Tn;
  const int M = Cg * Tn;
  const int tid = threadIdx.x;

  float sum = 0.f, ss = 0.f;
  for (int i = tid * 4; i < M; i += 256 * 4) {
    float4 v = *(const float4*)(x + base + i);
    sum += v.x + v.y + v.z + v.w;
    ss  += v.x * v.x + v.y * v.y + v.z * v.z + v.w * v.w;
  }
#pragma unroll
  for (int off = 32; off > 0; off >>= 1) {
    sum += __shfl_down(sum, off);
    ss  += __shfl_down(ss, off);
  }
  __shared__ float s1[4], s2[4];
  __shared__ float smean, sinv;
  const int wid = tid >> 6, lane = tid & 63;
  if (lane == 0) { s1[wid] = sum; s2[wid] = ss; }
  __syncthreads();
  if (tid == 0) {
    float t1 = s1[0] + s1[1] + s1[2] + s1[3];
    float t2 = s2[0] + s2[1] + s2[2] + s2[3];
    float mean = t1 / (float)M;
    float var  = t2 / (float)M - mean * mean;
    smean = mean;
    sinv  = rsqrtf(var + EPS_GN);
  }
  __syncthreads();
  const float mean = smean, inv = sinv;
  for (int i = tid * 4; i < M; i += 256 * 4) {
    float4 v = *(const float4*)(x + base + i);
    const int ch = g * Cg + (i >> tshift);
    const float sc = gamma[ch] * inv;
    const float sh = beta[ch] - mean * sc;
    v.x = fmaxf(v.x * sc + sh, 0.f);
    v.y = fmaxf(v.y * sc + sh, 0.f);
    v.z = fmaxf(v.z * sc + sh, 0.f);
    v.w = fmaxf(v.w * sc + sh, 0.f);
    *(float4*)(x + base + i) = v;
  }
}

extern "C" void kernel_launch(void* const* d_in, const int* in_sizes, int n_in,
                              void* d_out, int out_size, void* d_ws, size_t ws_size,
                              hipStream_t stream)
{
  (void)in_sizes; (void)n_in; (void)out_size; (void)ws_size;

  const float* feature  = (const float*)d_in[0];   // [4,512,2048]
  const float* frame    = (const float*)d_in[1];   // [4,256,4096]
  const float* segments = (const float*)d_in[2];   // [4,2048,4]
  const float* fsegs    = (const float*)d_in[3];   // [4,2048,4]
  const float* flc      = (const float*)d_in[4];   // [4,250,2048]
  const float* conf     = (const float*)d_in[5];   // [4,250,2048]
  const float* w_cur  = (const float*)d_in[6];
  const float* b_cur  = (const float*)d_in[7];
  const float* g_cur  = (const float*)d_in[8];
  const float* be_cur = (const float*)d_in[9];
  const float* w_lr   = (const float*)d_in[10];
  const float* b_lr   = (const float*)d_in[11];
  const float* g_lr   = (const float*)d_in[12];
  const float* be_lr  = (const float*)d_in[13];
  const float* w_roi  = (const float*)d_in[14];
  const float* b_roi  = (const float*)d_in[15];
  const float* g_roi  = (const float*)d_in[16];
  const float* be_roi = (const float*)d_in[17];
  const float* w_prop = (const float*)d_in[18];
  const float* b_prop = (const float*)d_in[19];
  const float* g_prop = (const float*)d_in[20];
  const float* be_prop= (const float*)d_in[21];

  // Outputs are FLOAT32: [out0 | feat], 4*512*2048 each.
  float* OUT0 = (float*)d_out;
  float* FOUT = (float*)d_out + 4194304;

  // ---- workspace layout ----
  float* ws  = (float*)d_ws;
  float* Y1  = ws;                 // fm_short  f32  4*256*2048
  float* RF  = Y1 + 2097152;       // roi block f32  4*256*2048
  ushort* U    = (ushort*)(RF + 2097152);
  ushort* FT   = U;                 // feature_t, then feat_t [4][2048][512]
  ushort* FRT  = FT + 4194304;      // frame_t   [4][4096][256]
  ushort* BMXF = FRT + 4194304;     // blockmax feat_t  [4][64][512]
  ushort* BMXR = BMXF + 131072;     // blockmax frame_t [4][128][256]
  ushort* RPT  = BMXR + 131072;     // roi pooled bf16 [4][2048][256]
  ushort* CATT = RPT + 2097152;     // cat_t [4][2048][1536]
  ushort* WCB  = CATT + 12582912;   // w_cur  bf16 [256][512]
  ushort* WLB  = WCB + 131072;      // w_lr   bf16 [512][512]
  ushort* WRB  = WLB + 262144;      // w_roi  bf16 [256][256]
  ushort* WPB  = WRB + 65536;       // w_prop bf16 [512][1536] padded
  // total ~66 MB

  // ---- weight casts ----
  cast_w_kernel<<<dim3(512),  256, 0, stream>>>(w_cur,  WCB, 512, 512, 131072);
  cast_w_kernel<<<dim3(1024), 256, 0, stream>>>(w_lr,   WLB, 512, 512, 262144);
  cast_w_kernel<<<dim3(256),  256, 0, stream>>>(w_roi,  WRB, 256, 256, 65536);
  cast_w_kernel<<<dim3(3072), 256, 0, stream>>>(w_prop, WPB, 1524, 1536, 786432);

  // ---- feature -> feature_t ----
  transpose_cast_off<<<dim3(64, 16, 4), 256, 0, stream>>>(feature, FT, 512, 2048, 512, 0, 512);

  // 1) fm_short = relu(GN(conv(feature, w_cur)))
  mfma_gemm<<<dim3(16, 2, 4), 256, 0, stream>>>(WCB, FT, b_cur, Y1, 256, 512, 2048);
  gn_relu_inplace<<<dim3(128), 256, 0, stream>>>(Y1, g_cur, be_cur, 256, 2048, 11);

  // 2) feat = relu(GN(conv(feature, w_lr)))  -> output 1
  mfma_gemm<<<dim3(16, 4, 4), 256, 0, stream>>>(WLB, FT, b_lr, FOUT, 512, 512, 2048);
  gn_relu_inplace<<<dim3(128), 256, 0, stream>>>(FOUT, g_lr, be_lr, 512, 2048, 11);

  // 3) feat -> feat_t (reuse FT); blockmax; pool into CATT[.,.,256:768)
  //    C=512 -> per-half 256 ch -> CHL=4 (64*4 == 256)
  transpose_cast_off<<<dim3(64, 16, 4), 256, 0, stream>>>(FOUT, FT, 512, 2048, 512, 0, 512);
  bmxt_kernel<<<dim3(64), 256, 0, stream>>>(FT, BMXF, 512, 2048, 64, 16384);
  pool_t_kernel<4><<<dim3(512, 2, 4), 256, 0, stream>>>(
      FT, BMXF, segments, CATT, 512, 2048, 64, 2048, 1536, 256);

  // 4) frame -> frame_t; blockmax; pool into RPT
  //    C=256 -> per-half 128 ch -> CHL=2 (64*2 == 128)
  transpose_cast_off<<<dim3(128, 8, 4), 256, 0, stream>>>(frame, FRT, 256, 4096, 256, 0, 256);
  bmxt_kernel<<<dim3(64), 256, 0, stream>>>(FRT, BMXR, 256, 4096, 128, 16384);
  pool_t_kernel<2><<<dim3(512, 2, 4), 256, 0, stream>>>(
      FRT, BMXR, fsegs, RPT, 256, 4096, 128, 2048, 256, 0);

  // 5) prop_roi = relu(GN(conv(roi_pooled, w_roi)))
  mfma_gemm<<<dim3(16, 2, 4), 256, 0, stream>>>(WRB, RPT, b_roi, RF, 256, 256, 2048);
  gn_relu_inplace<<<dim3(128), 256, 0, stream>>>(RF, g_roi, be_roi, 256, 2048, 11);

  // 6) remaining cat slices: RF(0:256), Y1(768:1024), flc(1024:1274), conf(1274:1536 w/ pad)
  transpose_cast_off<<<dim3(64, 8, 4), 256, 0, stream>>>(RF,  CATT, 256, 2048, 1536, 0,    256);
  transpose_cast_off<<<dim3(64, 8, 4), 256, 0, stream>>>(Y1,  CATT, 256, 2048, 1536, 768,  256);
  transpose_cast_off<<<dim3(64, 8, 4), 256, 0, stream>>>(flc, CATT, 250, 2048, 1536, 1024, 250);
  transpose_cast_off<<<dim3(64, 9, 4), 256, 0, stream>>>(conf,CATT, 250, 2048, 1536, 1274, 262);

  // 7) out0 = relu(GN(conv(cat, w_prop)))
  mfma_gemm<<<dim3(16, 4, 4), 256, 0, stream>>>(WPB, CATT, b_prop, OUT0, 512, 1536, 2048);
  gn_relu_inplace<<<dim3(128), 256, 0, stream>>>(OUT0, g_prop, be_prop, 512, 2048, 11);
}

// Round 10
// 413.705 us; speedup vs baseline: 2.6464x; 1.1670x over previous
//
#include <hip/hip_runtime.h>
#include <hip/hip_bf16.h>

#define GROUPS 32
#define EPS_GN 1e-5f

typedef short bf16x8 __attribute__((ext_vector_type(8)));
typedef float f32x4 __attribute__((ext_vector_type(4)));

__device__ __forceinline__ ushort to_bf16_bits(float v) {
  __hip_bfloat16 h = __float2bfloat16(v);
  return *(ushort*)&h;
}
__device__ __forceinline__ float bflo(unsigned u) { return __uint_as_float(u << 16); }
__device__ __forceinline__ float bfhi(unsigned u) { return __uint_as_float(u & 0xffff0000u); }
__device__ __forceinline__ ushort bfpack(float f) {
  return (ushort)(__float_as_uint(f) >> 16);   // exact: values originate from bf16
}

// ---------------- weight cast f32 [O][K] -> bf16 [O][Kp] (zero pad K..Kp) --------
__global__ __launch_bounds__(256)
void cast_w_kernel(const float* __restrict__ w, ushort* __restrict__ wb,
                   int K, int Kp, int total)
{
  int idx = blockIdx.x * 256 + threadIdx.x;
  if (idx >= total) return;
  int o = idx / Kp, k = idx - o * Kp;
  float v = (k < K) ? w[(size_t)o * K + k] : 0.f;
  wb[idx] = to_bf16_bits(v);
}

// ------- transpose+cast with offset: f32 [B][C][T] -> bf16 dst[b][t][coff+c] -----
__global__ __launch_bounds__(256)
void transpose_cast_off(const float* __restrict__ src, ushort* __restrict__ dst,
                        int C, int T, int dstride, int coff, int Cpad)
{
  __shared__ float tile[32][33];
  const int b = blockIdx.z;
  const int c0 = blockIdx.y * 32, t0 = blockIdx.x * 32;
  const int tx = threadIdx.x & 31, ty = threadIdx.x >> 5;   // 32 x 8
#pragma unroll
  for (int i = 0; i < 4; ++i) {
    const int c = c0 + ty + 8 * i;
    tile[ty + 8 * i][tx] = (c < C) ? src[((size_t)b * C + c) * T + t0 + tx] : 0.f;
  }
  __syncthreads();
  const int cw = c0 + tx;
  if (cw >= Cpad) return;
#pragma unroll
  for (int i = 0; i < 4; ++i)
    dst[((size_t)b * T + t0 + ty + 8 * i) * dstride + coff + cw] =
        to_bf16_bits(tile[tx][ty + 8 * i]);
}

// ---- generic row-group maxima: dst[rt][c] = max over `rows` consecutive src rows --
// src laid out [R_out*rows][C] flat; out index rt covers b,t jointly (contiguous).
__global__ __launch_bounds__(256)
void bmx_reduce(const ushort* __restrict__ src, ushort* __restrict__ dst,
                int C, int rows, int total8)
{
  int idx = blockIdx.x * 256 + threadIdx.x;
  if (idx >= total8) return;
  const int nc8 = C >> 3;
  const int ci = idx % nc8;
  const int rt = idx / nc8;
  const ushort* p = src + (size_t)rt * rows * C + ci * 8;
  float m[8];
#pragma unroll
  for (int i = 0; i < 8; ++i) m[i] = -3.402823466e38f;
  for (int j = 0; j < rows; ++j) {
    const uint4 v = *(const uint4*)(p + (size_t)j * C);
    m[0] = fmaxf(m[0], bflo(v.x)); m[1] = fmaxf(m[1], bfhi(v.x));
    m[2] = fmaxf(m[2], bflo(v.y)); m[3] = fmaxf(m[3], bfhi(v.y));
    m[4] = fmaxf(m[4], bflo(v.z)); m[5] = fmaxf(m[5], bfhi(v.z));
    m[6] = fmaxf(m[6], bflo(v.w)); m[7] = fmaxf(m[7], bfhi(v.w));
  }
  uint4 o;
  o.x = (unsigned)bfpack(m[0]) | ((unsigned)bfpack(m[1]) << 16);
  o.y = (unsigned)bfpack(m[2]) | ((unsigned)bfpack(m[3]) << 16);
  o.z = (unsigned)bfpack(m[4]) | ((unsigned)bfpack(m[5]) << 16);
  o.w = (unsigned)bfpack(m[6]) | ((unsigned)bfpack(m[7]) << 16);
  *(uint4*)(dst + (size_t)rt * C + ci * 8) = o;
}

// ------- transposed boundary max pool with 2-level tables (8- and 32-blocks) ------
// xt [B][T][C]; bx8 [B][T/8][C]; bx32 [B][T/32][C]; dst[(b*N+n)*dstride+coff+c]
// CHL channels/lane; INVARIANT 64*CHL == C/2. 4-deep unrolled scan (4 acc sets).
template<int CHL>
__global__ __launch_bounds__(256)
void pool_t_kernel(const ushort* __restrict__ xt, const ushort* __restrict__ bx32,
                   const ushort* __restrict__ bx8, const float* __restrict__ segs,
                   ushort* __restrict__ dst,
                   int C, int T, int TB32, int TB8, int N, int dstride, int coff)
{
  const int b    = blockIdx.z;
  const int half = blockIdx.y;
  const int n    = blockIdx.x * 4 + (threadIdx.x >> 6);
  const int lane = threadIdx.x & 63;
  const int c    = half * (C >> 1) + lane * CHL;

  const float4 sg = *(const float4*)(segs + ((size_t)b * N + n) * 4);
  const float f0 = half ? sg.z : sg.x;
  const float f1 = half ? sg.w : sg.y;
  int s = min(max((int)floorf(f0), 0), T - 1);
  int e = min(max((int)ceilf(f1), 0), T - 1);
  e = max(e, s);

  const ushort* xp  = xt  + (size_t)b * T    * C + c;
  const ushort* bp  = bx32+ (size_t)b * TB32 * C + c;
  const ushort* b8p = bx8 + (size_t)b * TB8  * C + c;

  float m[4][CHL];
#pragma unroll
  for (int u = 0; u < 4; ++u)
#pragma unroll
    for (int i = 0; i < CHL; ++i) m[u][i] = -3.402823466e38f;

  auto acc1 = [&](float* mm, const ushort* p) {
    if constexpr (CHL == 4) {
      const uint2 v = *(const uint2*)p;
      mm[0] = fmaxf(mm[0], bflo(v.x)); mm[1] = fmaxf(mm[1], bfhi(v.x));
      mm[2] = fmaxf(mm[2], bflo(v.y)); mm[3] = fmaxf(mm[3], bfhi(v.y));
    } else {
      const unsigned v = *(const unsigned*)p;
      mm[0] = fmaxf(mm[0], bflo(v)); mm[1] = fmaxf(mm[1], bfhi(v));
    }
  };
  // 4-deep unrolled scan over `cnt` rows of stride C
  auto scan = [&](const ushort* p, int cnt) {
    int i = 0;
    for (; i + 4 <= cnt; i += 4) {
      acc1(m[0], p);
      acc1(m[1], p + (size_t)C);
      acc1(m[2], p + 2 * (size_t)C);
      acc1(m[3], p + 3 * (size_t)C);
      p += 4 * (size_t)C;
    }
    for (; i < cnt; ++i) { acc1(m[0], p); p += (size_t)C; }
  };

  const int b0 = s >> 5, b1 = e >> 5;
  if (b0 == b1) {
    scan(xp + (size_t)s * C, e - s + 1);            // <= 32 rows
  } else {
    // left edge [s, t0e): scalar to 8-alignment, then 8-blocks
    const int t0e = (b0 + 1) << 5;
    const int a8 = (s + 7) & ~7;                    // a8 <= t0e (t0e 8-aligned)
    scan(xp + (size_t)s * C, a8 - s);               // <= 7 rows
    scan(b8p + (size_t)(a8 >> 3) * C, (t0e - a8) >> 3);   // <= 3 blocks
    // interior 32-blocks
    scan(bp + (size_t)(b0 + 1) * C, b1 - b0 - 1);
    // right edge [r0, e]: 8-blocks, then scalar tail
    const int r0 = b1 << 5;
    const int cnt8 = ((e + 1) >> 3) - (r0 >> 3);    // <= 4
    scan(b8p + (size_t)(r0 >> 3) * C, cnt8);
    const int ts = r0 + (cnt8 << 3);
    scan(xp + (size_t)ts * C, e - ts + 1);          // <= 7 rows
  }

#pragma unroll
  for (int i = 0; i < CHL; ++i)
    m[0][i] = fmaxf(fmaxf(m[0][i], m[1][i]), fmaxf(m[2][i], m[3][i]));

  ushort* op = dst + ((size_t)b * N + n) * dstride + coff + c;
  if constexpr (CHL == 4) {
    uint2 o;
    o.x = (unsigned)bfpack(m[0][0]) | ((unsigned)bfpack(m[0][1]) << 16);
    o.y = (unsigned)bfpack(m[0][2]) | ((unsigned)bfpack(m[0][3]) << 16);
    *(uint2*)op = o;
  } else {
    *(unsigned*)op = (unsigned)bfpack(m[0][0]) | ((unsigned)bfpack(m[0][1]) << 16);
  }
}

// ---------------- bf16 MFMA GEMM: out[b,o,t] = sum_k W[o,k]*Xt[b,t,k] + bias[o] --
__global__ __launch_bounds__(256)
void mfma_gemm(const ushort* __restrict__ Wb, const ushort* __restrict__ Xt,
               const float* __restrict__ bias, float* __restrict__ out,
               int O, int K, int T)
{
  const int b  = blockIdx.z;
  const int o0 = blockIdx.y * 128;
  const int t0 = blockIdx.x * 128;
  const int lane = threadIdx.x & 63;
  const int wid  = threadIdx.x >> 6;
  const int wm = wid >> 1, wn = wid & 1;
  const int lr = lane & 15;
  const int lq = lane >> 4;

  const ushort* wp = Wb + (size_t)(o0 + wm * 64 + lr) * K + lq * 8;
  const ushort* xp = Xt + ((size_t)b * T + t0 + wn * 64 + lr) * K + lq * 8;

  f32x4 acc[4][4];
#pragma unroll
  for (int i = 0; i < 4; ++i)
#pragma unroll
    for (int j = 0; j < 4; ++j) acc[i][j] = (f32x4){0.f, 0.f, 0.f, 0.f};

  for (int k0 = 0; k0 < K; k0 += 32) {
    bf16x8 a[4], bt[4];
#pragma unroll
    for (int i = 0; i < 4; ++i)
      a[i] = *(const bf16x8*)(wp + (size_t)i * 16 * K + k0);
#pragma unroll
    for (int j = 0; j < 4; ++j)
      bt[j] = *(const bf16x8*)(xp + (size_t)j * 16 * K + k0);
#pragma unroll
    for (int i = 0; i < 4; ++i)
#pragma unroll
      for (int j = 0; j < 4; ++j)
        acc[i][j] = __builtin_amdgcn_mfma_f32_16x16x32_bf16(a[i], bt[j], acc[i][j], 0, 0, 0);
  }

#pragma unroll
  for (int i = 0; i < 4; ++i) {
#pragma unroll
    for (int r = 0; r < 4; ++r) {
      const int o = o0 + wm * 64 + i * 16 + lq * 4 + r;
      const float bs = bias[o];
      float* op = out + ((size_t)b * O + o) * T + t0 + wn * 64 + lr;
#pragma unroll
      for (int j = 0; j < 4; ++j) op[j * 16] = acc[i][j][r] + bs;
    }
  }
}

// ---------------- GroupNorm(+ReLU) in-place over [B,C,Tn] ------------------------
__global__ __launch_bounds__(256)
void gn_relu_inplace(float* __restrict__ x, const float* __restrict__ gamma,
                     const float* __restrict__ beta, int C, int Tn, int tshift)
{
  const int b = blockIdx.x / GROUPS;
  const int g = blockIdx.x % GROUPS;
  const int Cg = C / GROUPS;
  const size_t base = ((size_t)b * C + (size_t)g * Cg) * Tn;
  const int M = Cg * Tn;
  const int tid = threadIdx.x;

  float sum = 0.f, ss = 0.f;
  for (int i = tid * 4; i < M; i += 256 * 4) {
    float4 v = *(const float4*)(x + base + i);
    sum += v.x + v.y + v.z + v.w;
    ss  += v.x * v.x + v.y * v.y + v.z * v.z + v.w * v.w;
  }
#pragma unroll
  for (int off = 32; off > 0; off >>= 1) {
    sum += __shfl_down(sum, off);
    ss  += __shfl_down(ss, off);
  }
  __shared__ float s1[4], s2[4];
  __shared__ float smean, sinv;
  const int wid = tid >> 6, lane = tid & 63;
  if (lane == 0) { s1[wid] = sum; s2[wid] = ss; }
  __syncthreads();
  if (tid == 0) {
    float t1 = s1[0] + s1[1] + s1[2] + s1[3];
    float t2 = s2[0] + s2[1] + s2[2] + s2[3];
    float mean = t1 / (float)M;
    float var  = t2 / (float)M - mean * mean;
    smean = mean;
    sinv  = rsqrtf(var + EPS_GN);
  }
  __syncthreads();
  const float mean = smean, inv = sinv;
  for (int i = tid * 4; i < M; i += 256 * 4) {
    float4 v = *(const float4*)(x + base + i);
    const int ch = g * Cg + (i >> tshift);
    const float sc = gamma[ch] * inv;
    const float sh = beta[ch] - mean * sc;
    v.x = fmaxf(v.x * sc + sh, 0.f);
    v.y = fmaxf(v.y * sc + sh, 0.f);
    v.z = fmaxf(v.z * sc + sh, 0.f);
    v.w = fmaxf(v.w * sc + sh, 0.f);
    *(float4*)(x + base + i) = v;
  }
}

extern "C" void kernel_launch(void* const* d_in, const int* in_sizes, int n_in,
                              void* d_out, int out_size, void* d_ws, size_t ws_size,
                              hipStream_t stream)
{
  (void)in_sizes; (void)n_in; (void)out_size; (void)ws_size;

  const float* feature  = (const float*)d_in[0];   // [4,512,2048]
  const float* frame    = (const float*)d_in[1];   // [4,256,4096]
  const float* segments = (const float*)d_in[2];   // [4,2048,4]
  const float* fsegs    = (const float*)d_in[3];   // [4,2048,4]
  const float* flc      = (const float*)d_in[4];   // [4,250,2048]
  const float* conf     = (const float*)d_in[5];   // [4,250,2048]
  const float* w_cur  = (const float*)d_in[6];
  const float* b_cur  = (const float*)d_in[7];
  const float* g_cur  = (const float*)d_in[8];
  const float* be_cur = (const float*)d_in[9];
  const float* w_lr   = (const float*)d_in[10];
  const float* b_lr   = (const float*)d_in[11];
  const float* g_lr   = (const float*)d_in[12];
  const float* be_lr  = (const float*)d_in[13];
  const float* w_roi  = (const float*)d_in[14];
  const float* b_roi  = (const float*)d_in[15];
  const float* g_roi  = (const float*)d_in[16];
  const float* be_roi = (const float*)d_in[17];
  const float* w_prop = (const float*)d_in[18];
  const float* b_prop = (const float*)d_in[19];
  const float* g_prop = (const float*)d_in[20];
  const float* be_prop= (const float*)d_in[21];

  // Outputs are FLOAT32: [out0 | feat], 4*512*2048 each.
  float* OUT0 = (float*)d_out;
  float* FOUT = (float*)d_out + 4194304;

  // ---- workspace layout ----
  float* ws  = (float*)d_ws;
  float* Y1  = ws;                 // fm_short  f32  4*256*2048
  float* RF  = Y1 + 2097152;       // roi block f32  4*256*2048
  ushort* U    = (ushort*)(RF + 2097152);
  ushort* FT   = U;                 // feature_t, then feat_t [4][2048][512]
  ushort* FRT  = FT + 4194304;      // frame_t   [4][4096][256]
  ushort* BX8F = FRT + 4194304;     // 8-block max feat_t  [4][256][512]
  ushort* BX32F= BX8F + 524288;     // 32-block max feat_t [4][64][512]
  ushort* BX8R = BX32F + 131072;    // 8-block max frame_t [4][512][256]
  ushort* BX32R= BX8R + 524288;     // 32-block max frame_t[4][128][256]
  ushort* RPT  = BX32R + 131072;    // roi pooled bf16 [4][2048][256]
  ushort* CATT = RPT + 2097152;     // cat_t [4][2048][1536]
  ushort* WCB  = CATT + 12582912;   // w_cur  bf16 [256][512]
  ushort* WLB  = WCB + 131072;      // w_lr   bf16 [512][512]
  ushort* WRB  = WLB + 262144;      // w_roi  bf16 [256][256]
  ushort* WPB  = WRB + 65536;       // w_prop bf16 [512][1536] padded
  // total ~68 MB

  // ---- weight casts ----
  cast_w_kernel<<<dim3(512),  256, 0, stream>>>(w_cur,  WCB, 512, 512, 131072);
  cast_w_kernel<<<dim3(1024), 256, 0, stream>>>(w_lr,   WLB, 512, 512, 262144);
  cast_w_kernel<<<dim3(256),  256, 0, stream>>>(w_roi,  WRB, 256, 256, 65536);
  cast_w_kernel<<<dim3(3072), 256, 0, stream>>>(w_prop, WPB, 1524, 1536, 786432);

  // ---- feature -> feature_t ----
  transpose_cast_off<<<dim3(64, 16, 4), 256, 0, stream>>>(feature, FT, 512, 2048, 512, 0, 512);

  // 1) fm_short = relu(GN(conv(feature, w_cur)))
  mfma_gemm<<<dim3(16, 2, 4), 256, 0, stream>>>(WCB, FT, b_cur, Y1, 256, 512, 2048);
  gn_relu_inplace<<<dim3(128), 256, 0, stream>>>(Y1, g_cur, be_cur, 256, 2048, 11);

  // 2) feat = relu(GN(conv(feature, w_lr)))  -> output 1
  mfma_gemm<<<dim3(16, 4, 4), 256, 0, stream>>>(WLB, FT, b_lr, FOUT, 512, 512, 2048);
  gn_relu_inplace<<<dim3(128), 256, 0, stream>>>(FOUT, g_lr, be_lr, 512, 2048, 11);

  // 3) feat -> feat_t (reuse FT); 2-level blockmax; pool into CATT[.,.,256:768)
  //    C=512 -> per-half 256 ch -> CHL=4
  transpose_cast_off<<<dim3(64, 16, 4), 256, 0, stream>>>(FOUT, FT, 512, 2048, 512, 0, 512);
  bmx_reduce<<<dim3(256), 256, 0, stream>>>(FT,   BX8F,  512, 8, 65536);
  bmx_reduce<<<dim3(64),  256, 0, stream>>>(BX8F, BX32F, 512, 4, 16384);
  pool_t_kernel<4><<<dim3(512, 2, 4), 256, 0, stream>>>(
      FT, BX32F, BX8F, segments, CATT, 512, 2048, 64, 256, 2048, 1536, 256);

  // 4) frame -> frame_t; 2-level blockmax; pool into RPT
  //    C=256 -> per-half 128 ch -> CHL=2
  transpose_cast_off<<<dim3(128, 8, 4), 256, 0, stream>>>(frame, FRT, 256, 4096, 256, 0, 256);
  bmx_reduce<<<dim3(256), 256, 0, stream>>>(FRT,  BX8R,  256, 8, 65536);
  bmx_reduce<<<dim3(64),  256, 0, stream>>>(BX8R, BX32R, 256, 4, 16384);
  pool_t_kernel<2><<<dim3(512, 2, 4), 256, 0, stream>>>(
      FRT, BX32R, BX8R, fsegs, RPT, 256, 4096, 128, 512, 2048, 256, 0);

  // 5) prop_roi = relu(GN(conv(roi_pooled, w_roi)))
  mfma_gemm<<<dim3(16, 2, 4), 256, 0, stream>>>(WRB, RPT, b_roi, RF, 256, 256, 2048);
  gn_relu_inplace<<<dim3(128), 256, 0, stream>>>(RF, g_roi, be_roi, 256, 2048, 11);

  // 6) remaining cat slices: RF(0:256), Y1(768:1024), flc(1024:1274), conf(1274:1536 w/ pad)
  transpose_cast_off<<<dim3(64, 8, 4), 256, 0, stream>>>(RF,  CATT, 256, 2048, 1536, 0,    256);
  transpose_cast_off<<<dim3(64, 8, 4), 256, 0, stream>>>(Y1,  CATT, 256, 2048, 1536, 768,  256);
  transpose_cast_off<<<dim3(64, 8, 4), 256, 0, stream>>>(flc, CATT, 250, 2048, 1536, 1024, 250);
  transpose_cast_off<<<dim3(64, 9, 4), 256, 0, stream>>>(conf,CATT, 250, 2048, 1536, 1274, 262);

  // 7) out0 = relu(GN(conv(cat, w_prop)))
  mfma_gemm<<<dim3(16, 4, 4), 256, 0, stream>>>(WPB, CATT, b_prop, OUT0, 512, 1536, 2048);
  gn_relu_inplace<<<dim3(128), 256, 0, stream>>>(OUT0, g_prop, be_prop, 512, 2048, 11);
}